// Round 9
// baseline (2213.042 us; speedup 1.0000x reference)
//
#include <hip/hip_runtime.h>

#define BG 8
#define NP 4096
#define MC 2048
#define KN 64

// Exact-rounding squared distance matching JAX/np f32 semantics.
__device__ __forceinline__ float dist2(float ax, float ay, float az,
                                       float bx, float by, float bz) {
    float dx = __fsub_rn(ax, bx), dy = __fsub_rn(ay, by), dz = __fsub_rn(az, bz);
    return __fadd_rn(__fadd_rn(__fmul_rn(dx, dx), __fmul_rn(dy, dy)), __fmul_rn(dz, dz));
}

template <int CTRL>
__device__ __forceinline__ float dppmax(float v) {
    int t = __builtin_amdgcn_update_dpp(0, __float_as_int(v), CTRL, 0xf, 0xf, true);
    return fmaxf(v, __int_as_float(t));
}
template <int CTRL>
__device__ __forceinline__ float dppmov(float v) {
    return __int_as_float(__builtin_amdgcn_update_dpp(0, __float_as_int(v), CTRL, 0xf, 0xf, true));
}

// ---- Kernel 1: FPS (blocks 0..7, 4 waves x 16 pts/thread) + y = x@W1x + b1 (blocks 8..519) ----
// (256,1): point arrays (48 regs) + candidate + result buffer (24) must be register-resident.
__global__ __launch_bounds__(256, 1) void k1_fps_y(
    const float* __restrict__ pos, const float* __restrict__ x,
    const float* __restrict__ w1, const float* __restrict__ b1,
    float* __restrict__ y,
    float* __restrict__ out_pos, float* __restrict__ out_batch)
{
    __shared__ float smem[12480];
    const int tid = threadIdx.x;
    if (blockIdx.x < BG) {
        const int b = blockIdx.x;
        const float* pg = pos + (size_t)b * NP * 3;
        for (int i = tid; i < NP * 3; i += 256) smem[i] = pg[i];
        __syncthreads();
        const int lane = tid & 63, wq = tid >> 6;   // 4 waves
        float px[16], py[16], pz[16], mind[16];
        const int base = tid * 16;
        #pragma unroll
        for (int i = 0; i < 16; i++) {
            px[i] = smem[(base + i) * 3];
            py[i] = smem[(base + i) * 3 + 1];
            pz[i] = smem[(base + i) * 3 + 2];
            mind[i] = 1e30f;
        }
        float4* slotA = (float4*)(smem + 12288);    // [2][4] : (V, x, y, z) double-buffered
        float cx = smem[0], cy = smem[1], cz = smem[2];
        // result buffer: thread owns centers m = tid*8 + s (s=0..7)
        float rbx[8], rby[8], rbz[8];
        #pragma unroll
        for (int s = 0; s < 8; s++) { rbx[s] = cx; rby[s] = cy; rbz[s] = cz; }
        for (int m = 1; m < MC; m++) {
            // update min distances; track thread-local (max, candidate pos) in registers
            float bv = -1.0f, wx = cx, wy = cy, wz = cz;
            #pragma unroll
            for (int i = 0; i < 16; i++) {
                float d = dist2(px[i], py[i], pz[i], cx, cy, cz);
                float nm = fminf(mind[i], d);
                mind[i] = nm;
                bool t = nm > bv;           // strict > keeps first (lowest) index
                bv = t ? nm : bv;
                wx = t ? px[i] : wx; wy = t ? py[i] : wy; wz = t ? pz[i] : wz;
            }
            // wave max via DPP
            float v = bv;
            v = dppmax<0x111>(v);  // row_shr:1
            v = dppmax<0x112>(v);  // row_shr:2
            v = dppmax<0x114>(v);  // row_shr:4
            v = dppmax<0x118>(v);  // row_shr:8
            v = dppmax<0x142>(v);  // row_bcast:15
            v = dppmax<0x143>(v);  // row_bcast:31
            const float V = __int_as_float(__builtin_amdgcn_readlane(__float_as_int(v), 63));
            // first candidate lane = min index (lane order == index order within wave)
            unsigned long long mk = __ballot(bv == V);
            const int db = (m & 1) * 4;
            if (lane == (int)(__ffsll((long long)mk) - 1))
                slotA[db + wq] = make_float4(bv, wx, wy, wz);   // straight from registers
            __syncthreads();
            // lane-parallel fold: one float4 read/thread (4 addrs -> broadcast groups),
            // 2 DPP tournament steps; tie-break: lower wave wins on equal V.
            float4 s = slotA[db + (lane & 3)];
            {   // xor1: quad_perm [1,0,3,2]
                float4 o;
                o.x = dppmov<0xB1>(s.x); o.y = dppmov<0xB1>(s.y);
                o.z = dppmov<0xB1>(s.z); o.w = dppmov<0xB1>(s.w);
                bool take = (o.x > s.x) || ((lane & 1) && o.x == s.x);
                s.x = take ? o.x : s.x; s.y = take ? o.y : s.y;
                s.z = take ? o.z : s.z; s.w = take ? o.w : s.w;
            }
            {   // xor2: quad_perm [2,3,0,1]
                float4 o;
                o.x = dppmov<0x4E>(s.x); o.y = dppmov<0x4E>(s.y);
                o.z = dppmov<0x4E>(s.z); o.w = dppmov<0x4E>(s.w);
                bool take = (o.x > s.x) || ((lane & 2) && o.x == s.x);
                s.x = take ? o.x : s.x; s.y = take ? o.y : s.y;
                s.z = take ? o.z : s.z; s.w = take ? o.w : s.w;
            }
            cx = s.y; cy = s.z; cz = s.w;
            // buffer result in the owning thread's registers
            if ((m >> 3) == tid) {
                switch (m & 7) {
                    case 0: rbx[0] = cx; rby[0] = cy; rbz[0] = cz; break;
                    case 1: rbx[1] = cx; rby[1] = cy; rbz[1] = cz; break;
                    case 2: rbx[2] = cx; rby[2] = cy; rbz[2] = cz; break;
                    case 3: rbx[3] = cx; rby[3] = cy; rbz[3] = cz; break;
                    case 4: rbx[4] = cx; rby[4] = cy; rbz[4] = cz; break;
                    case 5: rbx[5] = cx; rby[5] = cy; rbz[5] = cz; break;
                    case 6: rbx[6] = cx; rby[6] = cy; rbz[6] = cz; break;
                    default: rbx[7] = cx; rby[7] = cy; rbz[7] = cz; break;
                }
            }
        }
        // write out this thread's 8 centers (24 contiguous floats)
        const int c0 = b * MC + tid * 8;
        #pragma unroll
        for (int s = 0; s < 8; s++) {
            out_pos[(size_t)(c0 + s) * 3 + 0] = rbx[s];
            out_pos[(size_t)(c0 + s) * 3 + 1] = rby[s];
            out_pos[(size_t)(c0 + s) * 3 + 2] = rbz[s];
            out_batch[c0 + s] = (float)b;
        }
    } else {
        // -------- y = x @ W1x + b1 (64 points per block) --------
        const int q = blockIdx.x - BG;   // 0..511
        const int p0 = q * 64;
        float* xs = smem;                 // 64 x 65 (padded)
        float* wsm = smem + 4160;         // 64 x 64
        float* bsm = smem + 8256;         // 64
        for (int i = tid; i < 4096; i += 256) {
            xs[(i >> 6) * 65 + (i & 63)] = x[(size_t)p0 * 64 + i];
            wsm[i] = w1[i];               // first 64 rows of w1 = x-part
        }
        if (tid < 64) bsm[tid] = b1[tid];
        __syncthreads();
        const int pl = tid >> 2, oq = tid & 3;
        float acc[16];
        #pragma unroll
        for (int u = 0; u < 16; u++) acc[u] = bsm[oq * 16 + u];
        for (int f = 0; f < 64; f++) {
            float xv = xs[pl * 65 + f];
            const float4* wp = (const float4*)&wsm[f * 64 + oq * 16];
            float4 a = wp[0], b4 = wp[1], c4 = wp[2], d4 = wp[3];
            acc[0] = fmaf(xv, a.x, acc[0]);   acc[1] = fmaf(xv, a.y, acc[1]);
            acc[2] = fmaf(xv, a.z, acc[2]);   acc[3] = fmaf(xv, a.w, acc[3]);
            acc[4] = fmaf(xv, b4.x, acc[4]);  acc[5] = fmaf(xv, b4.y, acc[5]);
            acc[6] = fmaf(xv, b4.z, acc[6]);  acc[7] = fmaf(xv, b4.w, acc[7]);
            acc[8] = fmaf(xv, c4.x, acc[8]);  acc[9] = fmaf(xv, c4.y, acc[9]);
            acc[10] = fmaf(xv, c4.z, acc[10]); acc[11] = fmaf(xv, c4.w, acc[11]);
            acc[12] = fmaf(xv, d4.x, acc[12]); acc[13] = fmaf(xv, d4.y, acc[13]);
            acc[14] = fmaf(xv, d4.z, acc[14]); acc[15] = fmaf(xv, d4.w, acc[15]);
        }
        float4* yo = (float4*)&y[((size_t)p0 + pl) * 64 + oq * 16];
        yo[0] = make_float4(acc[0], acc[1], acc[2], acc[3]);
        yo[1] = make_float4(acc[4], acc[5], acc[6], acc[7]);
        yo[2] = make_float4(acc[8], acc[9], acc[10], acc[11]);
        yo[3] = make_float4(acc[12], acc[13], acc[14], acc[15]);
    }
}

// ---------------- Kernel 2: radius-capped kNN per center (centers from out_pos) -------------
__global__ __launch_bounds__(256) void k2_nbr(
    const float* __restrict__ pos, const float* __restrict__ out_pos,
    int* __restrict__ nbr, int* __restrict__ cntg)
{
    __shared__ float smem[12288 + 4 * 480 * 2];
    const int tid = threadIdx.x, lane = tid & 63, wv = tid >> 6;
    const int b = blockIdx.x >> 5, blk = blockIdx.x & 31;
    const float* pg = pos + (size_t)b * NP * 3;
    for (int i = tid; i < NP * 3; i += 256) smem[i] = pg[i];
    __syncthreads();
    float2* cb = (float2*)(smem + 12288) + wv * 480;
    const int wi = blk * 4 + wv;    // 0..127
    for (int t = 0; t < 16; t++) {
        const int m = wi + 128 * t, ci = b * MC + m;
        const float cx = out_pos[(size_t)ci * 3], cy = out_pos[(size_t)ci * 3 + 1], cz = out_pos[(size_t)ci * 3 + 2];
        int cnt = 0;
        for (int c = 0; c < 64; c++) {
            const int p = c * 64 + lane;
            float d2 = dist2(smem[p * 3], smem[p * 3 + 1], smem[p * 3 + 2], cx, cy, cz);
            bool inr = d2 <= 0.25f;
            unsigned long long mk = __ballot(inr);
            int pre = __popcll(mk & ((1ull << lane) - 1ull));
            int wp = cnt + pre;
            if (inr && wp < 480) cb[wp] = make_float2(d2, __int_as_float(p));
            cnt += __popcll(mk);
        }
        if (cnt > 480) cnt = 480;
        if (cnt <= KN) {
            if (lane < cnt) { float2 e = cb[lane]; nbr[(size_t)ci * KN + lane] = __float_as_int(e.y); }
            if (lane == 0) cntg[ci] = cnt;
        } else {
            for (int basej = 0; basej < cnt; basej += 64) {
                int jj = basej + lane;
                float dj = 3.4e38f; int ij = 0x7fffffff;
                bool act = jj < cnt;
                if (act) { float2 e = cb[jj]; dj = e.x; ij = __float_as_int(e.y); }
                int rank = 0;
                for (int l = 0; l < cnt; l++) {
                    float2 e = cb[l];
                    float dl = e.x; int il = __float_as_int(e.y);
                    if (dl < dj || (dl == dj && il < ij)) rank++;
                }
                if (act && rank < KN) nbr[(size_t)ci * KN + rank] = ij;
            }
            if (lane == 0) cntg[ci] = KN;
        }
    }
}

// ------- Kernel 3: per-center MLP + masked max (1 center/wave, prefetch pipeline) -------
__global__ __launch_bounds__(256, 1) void k3_mlp(
    const float* __restrict__ y, const float* __restrict__ pos,
    const int* __restrict__ nbr, const int* __restrict__ cntg,
    const float* __restrict__ w1, const float* __restrict__ w2, const float* __restrict__ b2,
    const float* __restrict__ w3, const float* __restrict__ b3,
    const float* __restrict__ out_pos, float* __restrict__ out_x)
{
    __shared__ float smem[4 * 136];
    const int tid = threadIdx.x, o = tid & 63, wv = tid >> 6;
    float w2c[64], w3a[64], w3b[64];
    #pragma unroll
    for (int f = 0; f < 64; f++) {
        w2c[f] = w2[f * 64 + o];
        w3a[f] = w3[f * 128 + o];
        w3b[f] = w3[f * 128 + 64 + o];
    }
    const float b2v = b2[o], b3av = b3[o], b3bv = b3[o + 64];
    const float wp0 = w1[64 * 64 + o], wp1 = w1[65 * 64 + o], wp2 = w1[66 * 64 + o];
    float* st1 = smem + wv * 136;
    float* st2 = st1 + 68;
    const int ci = blockIdx.x * 4 + wv;   // 0..16383
    const int b = ci >> 11;               // / MC
    const int kc = cntg[ci];
    const float cx = out_pos[(size_t)ci * 3], cy = out_pos[(size_t)ci * 3 + 1], cz = out_pos[(size_t)ci * 3 + 2];
    {
        const int j0 = nbr[(size_t)ci * KN];
        const size_t pj0 = (size_t)b * NP + j0;
        float yv = y[pj0 * 64 + o];
        float jx = pos[pj0 * 3], jy = pos[pj0 * 3 + 1], jz = pos[pj0 * 3 + 2];
        float mA = -3.4e38f, mB = -3.4e38f;
        for (int k = 0; k < kc; k++) {
            const int kn = (k + 1 < kc) ? k + 1 : k;
            const int jn = nbr[(size_t)ci * KN + kn];
            const size_t pjn = (size_t)b * NP + jn;
            float yv_n = y[pjn * 64 + o];
            float jx_n = pos[pjn * 3], jy_n = pos[pjn * 3 + 1], jz_n = pos[pjn * 3 + 2];
            // ---- compute current message ----
            float rx = jx - cx, ry = jy - cy, rz = jz - cz;
            float h1 = fmaf(rx, wp0, yv);
            h1 = fmaf(ry, wp1, h1);
            h1 = fmaf(rz, wp2, h1);
            h1 = fmaxf(h1, 0.f);
            st1[o] = h1;
            float a2a = b2v, a2b = 0.f;
            #pragma unroll
            for (int fc = 0; fc < 16; fc += 2) {
                float4 hA = *(const float4*)&st1[fc * 4];
                float4 hB = *(const float4*)&st1[fc * 4 + 4];
                a2a = fmaf(hA.x, w2c[fc * 4], a2a);
                a2a = fmaf(hA.y, w2c[fc * 4 + 1], a2a);
                a2a = fmaf(hA.z, w2c[fc * 4 + 2], a2a);
                a2a = fmaf(hA.w, w2c[fc * 4 + 3], a2a);
                a2b = fmaf(hB.x, w2c[fc * 4 + 4], a2b);
                a2b = fmaf(hB.y, w2c[fc * 4 + 5], a2b);
                a2b = fmaf(hB.z, w2c[fc * 4 + 6], a2b);
                a2b = fmaf(hB.w, w2c[fc * 4 + 7], a2b);
            }
            float h2 = fmaxf(a2a + a2b, 0.f);
            st2[o] = h2;
            float a3 = b3av, a4 = b3bv;
            #pragma unroll
            for (int fc = 0; fc < 16; fc++) {
                float4 h = *(const float4*)&st2[fc * 4];
                a3 = fmaf(h.x, w3a[fc * 4], a3);
                a3 = fmaf(h.y, w3a[fc * 4 + 1], a3);
                a3 = fmaf(h.z, w3a[fc * 4 + 2], a3);
                a3 = fmaf(h.w, w3a[fc * 4 + 3], a3);
                a4 = fmaf(h.x, w3b[fc * 4], a4);
                a4 = fmaf(h.y, w3b[fc * 4 + 1], a4);
                a4 = fmaf(h.z, w3b[fc * 4 + 2], a4);
                a4 = fmaf(h.w, w3b[fc * 4 + 3], a4);
            }
            mA = fmaxf(mA, a3);
            mB = fmaxf(mB, a4);
            yv = yv_n; jx = jx_n; jy = jy_n; jz = jz_n;
        }
        out_x[(size_t)ci * 128 + o] = mA;
        out_x[(size_t)ci * 128 + 64 + o] = mB;
    }
}

extern "C" void kernel_launch(void* const* d_in, const int* in_sizes, int n_in,
                              void* d_out, int out_size, void* d_ws, size_t ws_size,
                              hipStream_t stream) {
    const float* x   = (const float*)d_in[0];
    const float* pos = (const float*)d_in[1];
    const float* w1  = (const float*)d_in[3];
    const float* b1  = (const float*)d_in[4];
    const float* w2  = (const float*)d_in[5];
    const float* b2  = (const float*)d_in[6];
    const float* w3  = (const float*)d_in[7];
    const float* b3  = (const float*)d_in[8];

    float* out_x     = (float*)d_out;                       // [B*M,128]
    float* out_pos   = out_x + (size_t)BG * MC * 128;       // [B*M,3]
    float* out_batch = out_pos + (size_t)BG * MC * 3;       // [B*M] (written as float)

    char* ws   = (char*)d_ws;
    float* y   = (float*)ws;                    // 8 MB: [B*N,64] = x@W1x + b1
    int* cntg  = (int*)(ws + 8454144);          // 64 KB
    int* nbr   = (int*)(ws + 8519680);          // 4 MB

    hipLaunchKernelGGL(k1_fps_y, dim3(BG + 512), dim3(256), 0, stream,
                       pos, x, w1, b1, y, out_pos, out_batch);
    hipLaunchKernelGGL(k2_nbr, dim3(256), dim3(256), 0, stream,
                       pos, out_pos, nbr, cntg);
    hipLaunchKernelGGL(k3_mlp, dim3(4096), dim3(256), 0, stream,
                       y, pos, nbr, cntg, w1, w2, b2, w3, b3, out_pos, out_x);
}

// Round 10
// 1669.793 us; speedup vs baseline: 1.3253x; 1.3253x over previous
//
#include <hip/hip_runtime.h>

#define BG 8
#define NP 4096
#define MC 2048
#define KN 64
#define NWK 248
#define CAND 480

// Exact-rounding squared distance matching JAX/np f32 semantics.
__device__ __forceinline__ float dist2(float ax, float ay, float az,
                                       float bx, float by, float bz) {
    float dx = __fsub_rn(ax, bx), dy = __fsub_rn(ay, by), dz = __fsub_rn(az, bz);
    return __fadd_rn(__fadd_rn(__fmul_rn(dx, dx), __fmul_rn(dy, dy)), __fmul_rn(dz, dz));
}

template <int CTRL>
__device__ __forceinline__ float dppmax(float v) {
    int t = __builtin_amdgcn_update_dpp(0, __float_as_int(v), CTRL, 0xf, 0xf, true);
    return fmaxf(v, __int_as_float(t));
}

// ---------------- Kernel 0: y = x @ W1x + b1 (64 points per block, 512 blocks) ----------------
__global__ __launch_bounds__(256) void k_pre(
    const float* __restrict__ x, const float* __restrict__ w1, const float* __restrict__ b1,
    float* __restrict__ y)
{
    __shared__ float smem[8384];
    const int tid = threadIdx.x;
    const int p0 = blockIdx.x * 64;
    float* xs = smem;                 // 64 x 65 (padded)
    float* wsm = smem + 4160;         // 64 x 64
    float* bsm = smem + 8256;         // 64
    for (int i = tid; i < 4096; i += 256) {
        xs[(i >> 6) * 65 + (i & 63)] = x[(size_t)p0 * 64 + i];
        wsm[i] = w1[i];               // first 64 rows of w1 = x-part
    }
    if (tid < 64) bsm[tid] = b1[tid];
    __syncthreads();
    const int pl = tid >> 2, oq = tid & 3;
    float acc[16];
    #pragma unroll
    for (int u = 0; u < 16; u++) acc[u] = bsm[oq * 16 + u];
    for (int f = 0; f < 64; f++) {
        float xv = xs[pl * 65 + f];
        const float4* wp = (const float4*)&wsm[f * 64 + oq * 16];
        float4 a = wp[0], b4 = wp[1], c4 = wp[2], d4 = wp[3];
        acc[0] = fmaf(xv, a.x, acc[0]);   acc[1] = fmaf(xv, a.y, acc[1]);
        acc[2] = fmaf(xv, a.z, acc[2]);   acc[3] = fmaf(xv, a.w, acc[3]);
        acc[4] = fmaf(xv, b4.x, acc[4]);  acc[5] = fmaf(xv, b4.y, acc[5]);
        acc[6] = fmaf(xv, b4.z, acc[6]);  acc[7] = fmaf(xv, b4.w, acc[7]);
        acc[8] = fmaf(xv, c4.x, acc[8]);  acc[9] = fmaf(xv, c4.y, acc[9]);
        acc[10] = fmaf(xv, c4.z, acc[10]); acc[11] = fmaf(xv, c4.w, acc[11]);
        acc[12] = fmaf(xv, d4.x, acc[12]); acc[13] = fmaf(xv, d4.y, acc[13]);
        acc[14] = fmaf(xv, d4.z, acc[14]); acc[15] = fmaf(xv, d4.w, acc[15]);
    }
    float4* yo = (float4*)&y[((size_t)p0 + pl) * 64 + oq * 16];
    yo[0] = make_float4(acc[0], acc[1], acc[2], acc[3]);
    yo[1] = make_float4(acc[4], acc[5], acc[6], acc[7]);
    yo[2] = make_float4(acc[8], acc[9], acc[10], acc[11]);
    yo[3] = make_float4(acc[12], acc[13], acc[14], acc[15]);
}

// ---------------- Fused kernel: FPS producers (blocks 0..7) + kNN/MLP consumers (8..255) ------
__global__ __launch_bounds__(512, 2) void k_fused(
    const float* __restrict__ pos, const float* __restrict__ y,
    const float* __restrict__ w1, const float* __restrict__ w2, const float* __restrict__ b2,
    const float* __restrict__ w3, const float* __restrict__ b3,
    float* __restrict__ out_pos, float* __restrict__ out_batch, float* __restrict__ out_x,
    int* __restrict__ prog)
{
    __shared__ float smem[12320];
    const int tid = threadIdx.x;
    if (blockIdx.x < BG) {
        // ======== FPS producer (R3-exact structure, 8 waves x 8 pts/thread) ========
        const int b = blockIdx.x;
        const float* pg = pos + (size_t)b * NP * 3;
        for (int i = tid; i < NP * 3; i += 512) smem[i] = pg[i];
        __syncthreads();
        const int lane = tid & 63, wv = tid >> 6;
        float px[8], py[8], pz[8], mind[8];
        const int base = tid * 8;
        #pragma unroll
        for (int i = 0; i < 8; i++) {
            px[i] = smem[(base + i) * 3];
            py[i] = smem[(base + i) * 3 + 1];
            pz[i] = smem[(base + i) * 3 + 2];
            mind[i] = 1e30f;
        }
        float2* sl = (float2*)(smem + NP * 3);   // 2 x 8 double-buffered (V, idx) slots
        float cx = smem[0], cy = smem[1], cz = smem[2];
        if (tid == 0) {
            const size_t c3 = (size_t)b * MC * 3;
            __hip_atomic_store(&out_pos[c3 + 0], cx, __ATOMIC_RELAXED, __HIP_MEMORY_SCOPE_AGENT);
            __hip_atomic_store(&out_pos[c3 + 1], cy, __ATOMIC_RELAXED, __HIP_MEMORY_SCOPE_AGENT);
            __hip_atomic_store(&out_pos[c3 + 2], cz, __ATOMIC_RELAXED, __HIP_MEMORY_SCOPE_AGENT);
        }
        for (int m = 1; m < MC; m++) {
            float bv = -1.0f; int bi = base;
            #pragma unroll
            for (int i = 0; i < 8; i++) {
                float d = dist2(px[i], py[i], pz[i], cx, cy, cz);
                float nm = fminf(mind[i], d);
                mind[i] = nm;
                if (nm > bv) { bv = nm; bi = base + i; }  // strict > keeps first idx
            }
            float v = bv;
            v = dppmax<0x111>(v);  // row_shr:1
            v = dppmax<0x112>(v);  // row_shr:2
            v = dppmax<0x114>(v);  // row_shr:4
            v = dppmax<0x118>(v);  // row_shr:8
            v = dppmax<0x142>(v);  // row_bcast:15
            v = dppmax<0x143>(v);  // row_bcast:31
            const float V = __int_as_float(__builtin_amdgcn_readlane(__float_as_int(v), 63));
            unsigned long long mk = __ballot(bv == V);
            float2* sb = sl + (m & 1) * 8;
            if (lane == (int)(__ffsll((long long)mk) - 1))
                sb[wv] = make_float2(V, __int_as_float(bi));
            __syncthreads();   // also drains thread 0's center-(m-1) stores (vmcnt)
            const float4* sq = (const float4*)sb;
            float4 q0 = sq[0], q1 = sq[1], q2 = sq[2], q3 = sq[3];
            float Vg = q0.x; int ig = __float_as_int(q0.y);
            if (q0.z > Vg) { Vg = q0.z; ig = __float_as_int(q0.w); }
            if (q1.x > Vg) { Vg = q1.x; ig = __float_as_int(q1.y); }
            if (q1.z > Vg) { Vg = q1.z; ig = __float_as_int(q1.w); }
            if (q2.x > Vg) { Vg = q2.x; ig = __float_as_int(q2.y); }
            if (q2.z > Vg) { Vg = q2.z; ig = __float_as_int(q2.w); }
            if (q3.x > Vg) { Vg = q3.x; ig = __float_as_int(q3.y); }
            if (q3.z > Vg) { Vg = q3.z; ig = __float_as_int(q3.w); }
            cx = smem[ig * 3]; cy = smem[ig * 3 + 1]; cz = smem[ig * 3 + 2];
            if (tid == 0) {
                const size_t c3 = (size_t)(b * MC + m) * 3;
                __hip_atomic_store(&out_pos[c3 + 0], cx, __ATOMIC_RELAXED, __HIP_MEMORY_SCOPE_AGENT);
                __hip_atomic_store(&out_pos[c3 + 1], cy, __ATOMIC_RELAXED, __HIP_MEMORY_SCOPE_AGENT);
                __hip_atomic_store(&out_pos[c3 + 2], cz, __ATOMIC_RELAXED, __HIP_MEMORY_SCOPE_AGENT);
                // centers 0..m-1 are drained (previous barrier waited vmcnt(0))
                __hip_atomic_store(&prog[b], m, __ATOMIC_RELAXED, __HIP_MEMORY_SCOPE_AGENT);
            }
        }
        __syncthreads();   // drain last center's stores
        if (tid == 0)
            __hip_atomic_store(&prog[b], MC, __ATOMIC_RELEASE, __HIP_MEMORY_SCOPE_AGENT);
        for (int i = tid; i < MC; i += 512) out_batch[b * MC + i] = (float)b;
    } else {
        // ======== Consumer: 8 independent waves, each owns a center stream ========
        const int w = blockIdx.x - BG;        // 0..247
        const int g = w & 7;                  // graph
        const int sub = w >> 3;               // 0..30
        const int lane = tid & 63, ww = tid >> 6;
        const int waveid = sub * 8 + ww;      // 0..247 within graph
        // per-wave LDS regions
        float2* cand = (float2*)smem + ww * CAND;            // floats [0, 7680)
        int* nlist = (int*)(smem + 7680) + ww * 64;          // floats [7680, 8192)
        float* st1 = smem + 8192 + ww * 136;                 // floats [8192, 9280)
        float* st2 = st1 + 68;
        // weights into registers
        float w2c[64], w3a[64], w3b[64];
        #pragma unroll
        for (int f = 0; f < 64; f++) {
            w2c[f] = w2[f * 64 + lane];
            w3a[f] = w3[f * 128 + lane];
            w3b[f] = w3[f * 128 + 64 + lane];
        }
        const float b2v = b2[lane], b3av = b3[lane], b3bv = b3[lane + 64];
        const float wp0 = w1[64 * 64 + lane], wp1 = w1[65 * 64 + lane], wp2 = w1[66 * 64 + lane];
        const float* pg = pos + (size_t)g * NP * 3;
        const float* yg = y + (size_t)g * NP * 64;
        for (int m = waveid; m < MC; m += NWK) {
            // wait for center m to be published
            while (__hip_atomic_load(&prog[g], __ATOMIC_ACQUIRE, __HIP_MEMORY_SCOPE_AGENT) <= m) {
                __builtin_amdgcn_s_sleep(8);
            }
            const int ci = g * MC + m;
            const size_t c3 = (size_t)ci * 3;
            const float cx = __hip_atomic_load(&out_pos[c3 + 0], __ATOMIC_RELAXED, __HIP_MEMORY_SCOPE_AGENT);
            const float cy = __hip_atomic_load(&out_pos[c3 + 1], __ATOMIC_RELAXED, __HIP_MEMORY_SCOPE_AGENT);
            const float cz = __hip_atomic_load(&out_pos[c3 + 2], __ATOMIC_RELAXED, __HIP_MEMORY_SCOPE_AGENT);
            // ---- radius-capped kNN (pos via global/L2; read-only input) ----
            int cnt = 0;
            for (int c = 0; c < 64; c++) {
                const int p = c * 64 + lane;
                float ppx = pg[p * 3], ppy = pg[p * 3 + 1], ppz = pg[p * 3 + 2];
                float d2 = dist2(ppx, ppy, ppz, cx, cy, cz);
                bool inr = d2 <= 0.25f;
                unsigned long long mk = __ballot(inr);
                int pre = __popcll(mk & ((1ull << lane) - 1ull));
                int wp = cnt + pre;
                if (inr && wp < CAND) cand[wp] = make_float2(d2, __int_as_float(p));
                cnt += __popcll(mk);
            }
            if (cnt > CAND) cnt = CAND;
            int kc;
            if (cnt <= KN) {
                kc = cnt;
                if (lane < cnt) nlist[lane] = __float_as_int(cand[lane].y);
            } else {
                kc = KN;
                for (int basej = 0; basej < cnt; basej += 64) {
                    int jj = basej + lane;
                    float dj = 3.4e38f; int ij = 0x7fffffff;
                    bool act = jj < cnt;
                    if (act) { float2 e = cand[jj]; dj = e.x; ij = __float_as_int(e.y); }
                    int rank = 0;
                    for (int l = 0; l < cnt; l++) {
                        float2 e = cand[l];
                        float dl = e.x; int il = __float_as_int(e.y);
                        if (dl < dj || (dl == dj && il < ij)) rank++;
                    }
                    if (act && rank < KN) nlist[rank] = ij;
                }
            }
            // ---- MLP + masked max ----
            float mA = -3.4e38f, mB = -3.4e38f;
            for (int k = 0; k < kc; k++) {
                const int j = nlist[k];
                const float yv = yg[(size_t)j * 64 + lane];
                const float jx = pg[j * 3], jy = pg[j * 3 + 1], jz = pg[j * 3 + 2];
                float rx = jx - cx, ry = jy - cy, rz = jz - cz;
                float h1 = fmaf(rx, wp0, yv);
                h1 = fmaf(ry, wp1, h1);
                h1 = fmaf(rz, wp2, h1);
                h1 = fmaxf(h1, 0.f);
                st1[lane] = h1;
                float a2a = b2v, a2b = 0.f;
                #pragma unroll
                for (int fc = 0; fc < 16; fc += 2) {
                    float4 hA = *(const float4*)&st1[fc * 4];
                    float4 hB = *(const float4*)&st1[fc * 4 + 4];
                    a2a = fmaf(hA.x, w2c[fc * 4], a2a);
                    a2a = fmaf(hA.y, w2c[fc * 4 + 1], a2a);
                    a2a = fmaf(hA.z, w2c[fc * 4 + 2], a2a);
                    a2a = fmaf(hA.w, w2c[fc * 4 + 3], a2a);
                    a2b = fmaf(hB.x, w2c[fc * 4 + 4], a2b);
                    a2b = fmaf(hB.y, w2c[fc * 4 + 5], a2b);
                    a2b = fmaf(hB.z, w2c[fc * 4 + 6], a2b);
                    a2b = fmaf(hB.w, w2c[fc * 4 + 7], a2b);
                }
                float h2 = fmaxf(a2a + a2b, 0.f);
                st2[lane] = h2;
                float a3 = b3av, a4 = b3bv;
                #pragma unroll
                for (int fc = 0; fc < 16; fc++) {
                    float4 h = *(const float4*)&st2[fc * 4];
                    a3 = fmaf(h.x, w3a[fc * 4], a3);
                    a3 = fmaf(h.y, w3a[fc * 4 + 1], a3);
                    a3 = fmaf(h.z, w3a[fc * 4 + 2], a3);
                    a3 = fmaf(h.w, w3a[fc * 4 + 3], a3);
                    a4 = fmaf(h.x, w3b[fc * 4], a4);
                    a4 = fmaf(h.y, w3b[fc * 4 + 1], a4);
                    a4 = fmaf(h.z, w3b[fc * 4 + 2], a4);
                    a4 = fmaf(h.w, w3b[fc * 4 + 3], a4);
                }
                mA = fmaxf(mA, a3);
                mB = fmaxf(mB, a4);
            }
            out_x[(size_t)ci * 128 + lane] = mA;
            out_x[(size_t)ci * 128 + 64 + lane] = mB;
        }
    }
}

extern "C" void kernel_launch(void* const* d_in, const int* in_sizes, int n_in,
                              void* d_out, int out_size, void* d_ws, size_t ws_size,
                              hipStream_t stream) {
    const float* x   = (const float*)d_in[0];
    const float* pos = (const float*)d_in[1];
    const float* w1  = (const float*)d_in[3];
    const float* b1  = (const float*)d_in[4];
    const float* w2  = (const float*)d_in[5];
    const float* b2  = (const float*)d_in[6];
    const float* w3  = (const float*)d_in[7];
    const float* b3  = (const float*)d_in[8];

    float* out_x     = (float*)d_out;                       // [B*M,128]
    float* out_pos   = out_x + (size_t)BG * MC * 128;       // [B*M,3]
    float* out_batch = out_pos + (size_t)BG * MC * 3;       // [B*M] (written as float)

    char* ws  = (char*)d_ws;
    float* y  = (float*)ws;                     // 8 MB: [B*N,64] = x@W1x + b1
    int* prog = (int*)(ws + 8388608);           // 8 ints: per-graph published-center count

    hipMemsetAsync(prog, 0, 8 * sizeof(int), stream);
    hipLaunchKernelGGL(k_pre, dim3(512), dim3(256), 0, stream, x, w1, b1, y);
    hipLaunchKernelGGL(k_fused, dim3(256), dim3(512), 0, stream,
                       pos, y, w1, w2, b2, w3, b3, out_pos, out_batch, out_x, prog);
}

// Round 12
// 1363.648 us; speedup vs baseline: 1.6229x; 1.2245x over previous
//
#include <hip/hip_runtime.h>

#define BG 8
#define NP 4096
#define MC 2048
#define KN 64
#define NWK 248
#define CAND 480

// Exact-rounding squared distance matching JAX/np f32 semantics.
__device__ __forceinline__ float dist2(float ax, float ay, float az,
                                       float bx, float by, float bz) {
    float dx = __fsub_rn(ax, bx), dy = __fsub_rn(ay, by), dz = __fsub_rn(az, bz);
    return __fadd_rn(__fadd_rn(__fmul_rn(dx, dx), __fmul_rn(dy, dy)), __fmul_rn(dz, dz));
}

template <int CTRL>
__device__ __forceinline__ float dppmax(float v) {
    int t = __builtin_amdgcn_update_dpp(0, __float_as_int(v), CTRL, 0xf, 0xf, true);
    return fmaxf(v, __int_as_float(t));
}

// ---- Fused kernel: FPS producers (blocks 0..7) + y-precompute/kNN/MLP consumers (8..255) ----
// 96 KB static LDS forces exactly 1 block per CU (160 KB LDS/CU) -> no co-residency.
__global__ __launch_bounds__(512, 1) void k_fused(
    const float* __restrict__ pos, const float* __restrict__ x,
    const float* __restrict__ w1, const float* __restrict__ b1,
    const float* __restrict__ w2, const float* __restrict__ b2,
    const float* __restrict__ w3, const float* __restrict__ b3,
    float* __restrict__ y,
    float* __restrict__ out_pos, float* __restrict__ out_batch, float* __restrict__ out_x,
    int* __restrict__ prog, int* __restrict__ yready)
{
    __shared__ float smem[24576];   // 96 KB
    const int tid = threadIdx.x;
    if (blockIdx.x < BG) {
        // ======== FPS producer (R3-exact structure, 8 waves x 8 pts/thread) ========
        const int b = blockIdx.x;
        const float* pg = pos + (size_t)b * NP * 3;
        for (int i = tid; i < NP * 3; i += 512) smem[i] = pg[i];
        __syncthreads();
        const int lane = tid & 63, wv = tid >> 6;
        float px[8], py[8], pz[8], mind[8];
        const int base = tid * 8;
        #pragma unroll
        for (int i = 0; i < 8; i++) {
            px[i] = smem[(base + i) * 3];
            py[i] = smem[(base + i) * 3 + 1];
            pz[i] = smem[(base + i) * 3 + 2];
            mind[i] = 1e30f;
        }
        float2* sl = (float2*)(smem + NP * 3);   // 2 x 8 double-buffered (V, idx) slots
        float cx = smem[0], cy = smem[1], cz = smem[2];
        if (tid == 0) {
            const size_t c3 = (size_t)b * MC * 3;
            __hip_atomic_store(&out_pos[c3 + 0], cx, __ATOMIC_RELAXED, __HIP_MEMORY_SCOPE_AGENT);
            __hip_atomic_store(&out_pos[c3 + 1], cy, __ATOMIC_RELAXED, __HIP_MEMORY_SCOPE_AGENT);
            __hip_atomic_store(&out_pos[c3 + 2], cz, __ATOMIC_RELAXED, __HIP_MEMORY_SCOPE_AGENT);
        }
        for (int m = 1; m < MC; m++) {
            float bv = -1.0f; int bi = base;
            #pragma unroll
            for (int i = 0; i < 8; i++) {
                float d = dist2(px[i], py[i], pz[i], cx, cy, cz);
                float nm = fminf(mind[i], d);
                mind[i] = nm;
                if (nm > bv) { bv = nm; bi = base + i; }  // strict > keeps first idx
            }
            float v = bv;
            v = dppmax<0x111>(v);  // row_shr:1
            v = dppmax<0x112>(v);  // row_shr:2
            v = dppmax<0x114>(v);  // row_shr:4
            v = dppmax<0x118>(v);  // row_shr:8
            v = dppmax<0x142>(v);  // row_bcast:15
            v = dppmax<0x143>(v);  // row_bcast:31
            const float V = __int_as_float(__builtin_amdgcn_readlane(__float_as_int(v), 63));
            unsigned long long mk = __ballot(bv == V);
            float2* sb = sl + (m & 1) * 8;
            if (lane == (int)(__ffsll((long long)mk) - 1))
                sb[wv] = make_float2(V, __int_as_float(bi));
            __syncthreads();   // also drains thread 0's center-(m-1) stores (vmcnt)
            const float4* sq = (const float4*)sb;
            float4 q0 = sq[0], q1 = sq[1], q2 = sq[2], q3 = sq[3];
            float Vg = q0.x; int ig = __float_as_int(q0.y);
            if (q0.z > Vg) { Vg = q0.z; ig = __float_as_int(q0.w); }
            if (q1.x > Vg) { Vg = q1.x; ig = __float_as_int(q1.y); }
            if (q1.z > Vg) { Vg = q1.z; ig = __float_as_int(q1.w); }
            if (q2.x > Vg) { Vg = q2.x; ig = __float_as_int(q2.y); }
            if (q2.z > Vg) { Vg = q2.z; ig = __float_as_int(q2.w); }
            if (q3.x > Vg) { Vg = q3.x; ig = __float_as_int(q3.y); }
            if (q3.z > Vg) { Vg = q3.z; ig = __float_as_int(q3.w); }
            cx = smem[ig * 3]; cy = smem[ig * 3 + 1]; cz = smem[ig * 3 + 2];
            if (tid == 0) {
                const size_t c3 = (size_t)(b * MC + m) * 3;
                __hip_atomic_store(&out_pos[c3 + 0], cx, __ATOMIC_RELAXED, __HIP_MEMORY_SCOPE_AGENT);
                __hip_atomic_store(&out_pos[c3 + 1], cy, __ATOMIC_RELAXED, __HIP_MEMORY_SCOPE_AGENT);
                __hip_atomic_store(&out_pos[c3 + 2], cz, __ATOMIC_RELAXED, __HIP_MEMORY_SCOPE_AGENT);
                // centers 0..m-1 are drained (previous barrier waited vmcnt(0))
                __hip_atomic_store(&prog[b * 16], m, __ATOMIC_RELAXED, __HIP_MEMORY_SCOPE_AGENT);
            }
        }
        __syncthreads();   // drain last center's stores
        if (tid == 0)
            __hip_atomic_store(&prog[b * 16], MC, __ATOMIC_RELEASE, __HIP_MEMORY_SCOPE_AGENT);
        for (int i = tid; i < MC; i += 512) out_batch[b * MC + i] = (float)b;
    } else {
        // ======== Consumer block ========
        const int w = blockIdx.x - BG;        // 0..247
        const int g = w & 7;                  // graph
        const int sub = w >> 3;               // 0..30
        const int lane = tid & 63, ww = tid >> 6;
        const int waveid = sub * 8 + ww;      // 0..247 within graph
        // ---- phase 1: y = x @ W1x + b1 for this block's chunk of graph g ----
        float* wsm = smem;                    // [0, 4096): W1 x-part
        for (int i = tid; i < 4096; i += 512) wsm[i] = w1[i];
        const float b1v = b1[lane];
        __syncthreads();
        const int p0 = sub * 133;
        const int p1 = (p0 + 133 < NP) ? p0 + 133 : NP;
        const float* xg = x + (size_t)g * NP * 64;
        float* yg_w = y + (size_t)g * NP * 64;
        for (int p = p0 + ww; p < p1; p += 8) {
            float xrow = xg[(size_t)p * 64 + lane];
            float acc = b1v;
            #pragma unroll
            for (int f = 0; f < 64; f++) {
                float xf = __shfl(xrow, f, 64);
                acc = fmaf(xf, wsm[f * 64 + lane], acc);
            }
            yg_w[(size_t)p * 64 + lane] = acc;
        }
        __syncthreads();                      // drain this block's y stores
        if (tid == 0)
            __hip_atomic_fetch_add(&yready[g * 16], 1, __ATOMIC_RELEASE, __HIP_MEMORY_SCOPE_AGENT);
        // ---- phase 2: preload weights into registers (overlaps the wait) ----
        float w2c[64], w3a[64], w3b[64];
        #pragma unroll
        for (int f = 0; f < 64; f++) {
            w2c[f] = w2[f * 64 + lane];
            w3a[f] = w3[f * 128 + lane];
            w3b[f] = w3[f * 128 + 64 + lane];
        }
        const float b2v = b2[lane], b3av = b3[lane], b3bv = b3[lane + 64];
        const float wp0 = w1[64 * 64 + lane], wp1 = w1[65 * 64 + lane], wp2 = w1[66 * 64 + lane];
        // gate: all 31 y-writer blocks of this graph done, then one acquire (cache inv)
        while (__hip_atomic_load(&yready[g * 16], __ATOMIC_RELAXED, __HIP_MEMORY_SCOPE_AGENT) < 31)
            __builtin_amdgcn_s_sleep(16);
        {
            int yr = __hip_atomic_load(&yready[g * 16], __ATOMIC_ACQUIRE, __HIP_MEMORY_SCOPE_AGENT);
            asm volatile("" :: "v"(yr));      // keep the acquire load alive
        }
        // per-wave LDS regions
        float2* cand = (float2*)(smem + 4096) + ww * CAND;   // floats [4096, 11776)
        int* nlist = (int*)(smem + 11776) + ww * 64;         // floats [11776, 12288)
        float* st1 = smem + 12288 + ww * 136;                // floats [12288, 13376)
        float* st2 = st1 + 68;
        const float* pg = pos + (size_t)g * NP * 3;
        const float* yg = y + (size_t)g * NP * 64;
        // ---- phase 3: per-center kNN + MLP, streaming behind the producer ----
        for (int m = waveid; m < MC; m += NWK) {
            int cur;
            while ((cur = __hip_atomic_load(&prog[g * 16], __ATOMIC_RELAXED, __HIP_MEMORY_SCOPE_AGENT)) <= m) {
                if (m - cur > 16) __builtin_amdgcn_s_sleep(64);
                else              __builtin_amdgcn_s_sleep(4);
            }
            const int ci = g * MC + m;
            const size_t c3 = (size_t)ci * 3;
            const float cx = __hip_atomic_load(&out_pos[c3 + 0], __ATOMIC_RELAXED, __HIP_MEMORY_SCOPE_AGENT);
            const float cy = __hip_atomic_load(&out_pos[c3 + 1], __ATOMIC_RELAXED, __HIP_MEMORY_SCOPE_AGENT);
            const float cz = __hip_atomic_load(&out_pos[c3 + 2], __ATOMIC_RELAXED, __HIP_MEMORY_SCOPE_AGENT);
            // ---- radius-capped kNN ----
            int cnt = 0;
            for (int c = 0; c < 64; c++) {
                const int p = c * 64 + lane;
                float ppx = pg[p * 3], ppy = pg[p * 3 + 1], ppz = pg[p * 3 + 2];
                float d2 = dist2(ppx, ppy, ppz, cx, cy, cz);
                bool inr = d2 <= 0.25f;
                unsigned long long mk = __ballot(inr);
                int pre = __popcll(mk & ((1ull << lane) - 1ull));
                int wp = cnt + pre;
                if (inr && wp < CAND) cand[wp] = make_float2(d2, __int_as_float(p));
                cnt += __popcll(mk);
            }
            if (cnt > CAND) cnt = CAND;
            int kc;
            if (cnt <= KN) {
                kc = cnt;
                if (lane < cnt) nlist[lane] = __float_as_int(cand[lane].y);
            } else {
                kc = KN;
                for (int basej = 0; basej < cnt; basej += 64) {
                    int jj = basej + lane;
                    float dj = 3.4e38f; int ij = 0x7fffffff;
                    bool act = jj < cnt;
                    if (act) { float2 e = cand[jj]; dj = e.x; ij = __float_as_int(e.y); }
                    int rank = 0;
                    for (int l = 0; l < cnt; l++) {
                        float2 e = cand[l];
                        float dl = e.x; int il = __float_as_int(e.y);
                        if (dl < dj || (dl == dj && il < ij)) rank++;
                    }
                    if (act && rank < KN) nlist[rank] = ij;
                }
            }
            // ---- MLP + masked max ----
            float mA = -3.4e38f, mB = -3.4e38f;
            for (int k = 0; k < kc; k++) {
                const int j = nlist[k];
                const float yv = yg[(size_t)j * 64 + lane];
                const float jx = pg[j * 3], jy = pg[j * 3 + 1], jz = pg[j * 3 + 2];
                float rx = jx - cx, ry = jy - cy, rz = jz - cz;
                float h1 = fmaf(rx, wp0, yv);
                h1 = fmaf(ry, wp1, h1);
                h1 = fmaf(rz, wp2, h1);
                h1 = fmaxf(h1, 0.f);
                st1[lane] = h1;
                float a2a = b2v, a2b = 0.f;
                #pragma unroll
                for (int fc = 0; fc < 16; fc += 2) {
                    float4 hA = *(const float4*)&st1[fc * 4];
                    float4 hB = *(const float4*)&st1[fc * 4 + 4];
                    a2a = fmaf(hA.x, w2c[fc * 4], a2a);
                    a2a = fmaf(hA.y, w2c[fc * 4 + 1], a2a);
                    a2a = fmaf(hA.z, w2c[fc * 4 + 2], a2a);
                    a2a = fmaf(hA.w, w2c[fc * 4 + 3], a2a);
                    a2b = fmaf(hB.x, w2c[fc * 4 + 4], a2b);
                    a2b = fmaf(hB.y, w2c[fc * 4 + 5], a2b);
                    a2b = fmaf(hB.z, w2c[fc * 4 + 6], a2b);
                    a2b = fmaf(hB.w, w2c[fc * 4 + 7], a2b);
                }
                float h2 = fmaxf(a2a + a2b, 0.f);
                st2[lane] = h2;
                float a3 = b3av, a4 = b3bv;
                #pragma unroll
                for (int fc = 0; fc < 16; fc++) {
                    float4 h = *(const float4*)&st2[fc * 4];
                    a3 = fmaf(h.x, w3a[fc * 4], a3);
                    a3 = fmaf(h.y, w3a[fc * 4 + 1], a3);
                    a3 = fmaf(h.z, w3a[fc * 4 + 2], a3);
                    a3 = fmaf(h.w, w3a[fc * 4 + 3], a3);
                    a4 = fmaf(h.x, w3b[fc * 4], a4);
                    a4 = fmaf(h.y, w3b[fc * 4 + 1], a4);
                    a4 = fmaf(h.z, w3b[fc * 4 + 2], a4);
                    a4 = fmaf(h.w, w3b[fc * 4 + 3], a4);
                }
                mA = fmaxf(mA, a3);
                mB = fmaxf(mB, a4);
            }
            out_x[(size_t)ci * 128 + lane] = mA;
            out_x[(size_t)ci * 128 + 64 + lane] = mB;
        }
    }
}

extern "C" void kernel_launch(void* const* d_in, const int* in_sizes, int n_in,
                              void* d_out, int out_size, void* d_ws, size_t ws_size,
                              hipStream_t stream) {
    const float* x   = (const float*)d_in[0];
    const float* pos = (const float*)d_in[1];
    const float* w1  = (const float*)d_in[3];
    const float* b1  = (const float*)d_in[4];
    const float* w2  = (const float*)d_in[5];
    const float* b2  = (const float*)d_in[6];
    const float* w3  = (const float*)d_in[7];
    const float* b3  = (const float*)d_in[8];

    float* out_x     = (float*)d_out;                       // [B*M,128]
    float* out_pos   = out_x + (size_t)BG * MC * 128;       // [B*M,3]
    float* out_batch = out_pos + (size_t)BG * MC * 3;       // [B*M] (written as float)

    char* ws    = (char*)d_ws;
    float* y    = (float*)ws;                   // 8 MB: [B*N,64] = x@W1x + b1
    int* prog   = (int*)(ws + 8388608);         // 8 x 16 ints (64B stride per graph)
    int* yready = (int*)(ws + 8389120);         // 8 x 16 ints

    (void)hipMemsetAsync(prog, 0, 1024, stream);  // prog + yready
    hipLaunchKernelGGL(k_fused, dim3(256), dim3(512), 0, stream,
                       pos, x, w1, b1, w2, b2, w3, b3,
                       y, out_pos, out_batch, out_x, prog, yready);
}